// Round 8
// baseline (261.406 us; speedup 1.0000x reference)
//
#include <hip/hip_runtime.h>
#include <hip/hip_bf16.h>
#include <math.h>
#include <stdint.h>

// Problem constants
#define BB 8
#define SS 1024
#define DMM 512
#define HH 8
#define DKK 32
#define DHH 64
// M = BB*SS = 8192

typedef __bf16 bf16x8 __attribute__((ext_vector_type(8)));
typedef float f32x4 __attribute__((ext_vector_type(4)));

// async 16B global->LDS (gfx950). LDS dest = wave-uniform base + lane*16.
__device__ __forceinline__ void gll16(const void* g, void* l) {
  __builtin_amdgcn_global_load_lds(
      (const __attribute__((address_space(1))) void*)(uintptr_t)g,
      (__attribute__((address_space(3))) void*)(uint32_t)(uintptr_t)l,
      16, 0, 0);
}

__device__ __forceinline__ uint4 pack8(const float4 a, const float4 b) {
  union { __hip_bfloat162 h2[4]; uint4 u; } p;
  p.h2[0] = __float22bfloat162_rn(make_float2(a.x, a.y));
  p.h2[1] = __float22bfloat162_rn(make_float2(a.z, a.w));
  p.h2[2] = __float22bfloat162_rn(make_float2(b.x, b.y));
  p.h2[3] = __float22bfloat162_rn(make_float2(b.z, b.w));
  return p.u;
}

// Split-attention entry table: per bh, 24 blocks sorted by descending work.
// j = s-tile (64 rows); [tb,te) = t-tile range. j>=8 is split in two halves.
__device__ __constant__ unsigned char dJ[24]  = {15,15,14,7,14,13,13,12,6,12,11,11,10,5,10,9,9,8,4,8,3,2,1,0};
__device__ __constant__ unsigned char dTB[24] = {0,8,0,0,8,0,7,0,0,7,0,6,0,0,6,0,5,0,0,5,0,0,0,0};
__device__ __constant__ unsigned char dTE[24] = {8,16,8,8,15,7,14,7,7,13,6,12,6,6,11,5,10,5,5,9,4,3,2,1};

// ---------------------------------------------------------------------------
// One-shot fp32->bf16 conversion of x, Wq|Wk|Wv (->Wcat), Wo, Wf. 2560 blocks.
// ---------------------------------------------------------------------------
__global__ __launch_bounds__(256) void cvt_all(
    const float* __restrict__ x, const float* __restrict__ Wq,
    const float* __restrict__ Wk, const float* __restrict__ Wv,
    const float* __restrict__ Wo, const float* __restrict__ Wf,
    __bf16* __restrict__ xb, __bf16* __restrict__ Wcat,
    __bf16* __restrict__ Wob, __bf16* __restrict__ Wfb) {
  size_t i = ((size_t)blockIdx.x * 256 + threadIdx.x) * 8;
  const float* s;
  __bf16* d;
  size_t off;
  if (i < 4194304) { s = x; d = xb + i; off = i; }
  else {
    size_t j = i - 4194304;
    if (j < 524288) {
      d = Wcat + j;
      if (j < 131072) { s = Wq; off = j; }
      else if (j < 262144) { s = Wk; off = j - 131072; }
      else { s = Wv; off = j - 262144; }
    } else {
      size_t jj = j - 524288;
      if (jj < 262144) { s = Wo; d = Wob + jj; off = jj; }
      else { s = Wf; d = Wfb + (jj - 262144); off = jj - 262144; }
    }
  }
  float4 a = *(const float4*)&s[off];
  float4 b = *(const float4*)&s[off + 4];
  *(uint4*)d = pack8(a, b);
}

// ---------------------------------------------------------------------------
// QKV GEMM, double-buffered K-loop (1 barrier/iter, loads fly over compute),
// fused epilogue: l2norm(q,k) -> bf16 Qg/Kg planes; v -> bf16 Vrow.
// ---------------------------------------------------------------------------
__global__ __launch_bounds__(256) void gemm_qkv(
    const __bf16* __restrict__ A, const __bf16* __restrict__ W,
    __bf16* __restrict__ Qg, __bf16* __restrict__ Kg,
    __bf16* __restrict__ Vrow) {
  __shared__ __bf16 As[2][128 * 32];
  __shared__ __bf16 Bs[2][128 * 32];
  const int tid = threadIdx.x;
  const int n0 = blockIdx.x * 128;
  const int m0 = blockIdx.y * 128;
  const int lane = tid & 63;
  const int w = tid >> 6;
  const int wm = (w & 1) * 64, wn = (w >> 1) * 64;
  const int fr = lane & 15, quad = lane >> 4;
  const int srow = lane >> 2;
  const int schunk = (lane & 3) ^ ((lane >> 3) & 3);

  f32x4 acc[4][4];
#pragma unroll
  for (int mi = 0; mi < 4; ++mi)
#pragma unroll
    for (int ni = 0; ni < 4; ++ni) acc[mi][ni] = (f32x4){0.f, 0.f, 0.f, 0.f};

  // prologue: stage k-tile 0 into buf 0
#pragma unroll
  for (int j = 0; j < 2; ++j) {
    const int seg = w * 2 + j;
    const int row = seg * 16 + srow;
    gll16(&A[(size_t)(m0 + row) * 512 + schunk * 8], &As[0][seg * 512]);
    gll16(&W[(size_t)(n0 + row) * 512 + schunk * 8], &Bs[0][seg * 512]);
  }
  for (int it = 0; it < 16; ++it) {
    __syncthreads();  // drains buf[it&1] loads + prior ds_reads
    if (it < 15) {
      const int kt = (it + 1) * 32, ib = (it + 1) & 1;
#pragma unroll
      for (int j = 0; j < 2; ++j) {
        const int seg = w * 2 + j;
        const int row = seg * 16 + srow;
        gll16(&A[(size_t)(m0 + row) * 512 + kt + schunk * 8], &As[ib][seg * 512]);
        gll16(&W[(size_t)(n0 + row) * 512 + kt + schunk * 8], &Bs[ib][seg * 512]);
      }
    }
    const __bf16* as = As[it & 1];
    const __bf16* bs = Bs[it & 1];
    bf16x8 af[4], bfv[4];
    const int rsw = (quad ^ ((fr >> 1) & 3)) * 8;
#pragma unroll
    for (int mi = 0; mi < 4; ++mi)
      af[mi] = *(const bf16x8*)&as[(wm + mi * 16 + fr) * 32 + rsw];
#pragma unroll
    for (int ni = 0; ni < 4; ++ni)
      bfv[ni] = *(const bf16x8*)&bs[(wn + ni * 16 + fr) * 32 + rsw];
#pragma unroll
    for (int mi = 0; mi < 4; ++mi)
#pragma unroll
      for (int ni = 0; ni < 4; ++ni)
        acc[mi][ni] = __builtin_amdgcn_mfma_f32_16x16x32_bf16(
            af[mi], bfv[ni], acc[mi][ni], 0, 0, 0);
  }

  const int er = quad * 4;
  const int ec = fr;
  if (n0 < 512) {
    const bool isq = (n0 < 256);
    __bf16* G = isq ? Qg : Kg;
    const int nb = isq ? n0 : n0 - 256;
#pragma unroll
    for (int mi = 0; mi < 4; ++mi) {
#pragma unroll
      for (int p = 0; p < 2; ++p) {
        const int hh = (nb + wn + p * 32) >> 5;
#pragma unroll
        for (int r = 0; r < 4; ++r) {
          float v0 = acc[mi][2 * p][r], v1 = acc[mi][2 * p + 1][r];
          float ss = v0 * v0 + v1 * v1;
          ss += __shfl_xor(ss, 1, 64);
          ss += __shfl_xor(ss, 2, 64);
          ss += __shfl_xor(ss, 4, 64);
          ss += __shfl_xor(ss, 8, 64);
          const float sc = 1.0f / fmaxf(sqrtf(ss), 1e-12f);
          const int mm = m0 + wm + mi * 16 + er + r;
          const int bb = mm >> 10, s = mm & 1023;
          __bf16* gp = G + ((size_t)(bb * 8 + hh) * 1024 + s) * 32;
          gp[ec] = (__bf16)(v0 * sc);
          gp[16 + ec] = (__bf16)(v1 * sc);
        }
      }
    }
  } else {
#pragma unroll
    for (int mi = 0; mi < 4; ++mi)
#pragma unroll
      for (int ni = 0; ni < 4; ++ni) {
        const int n = n0 - 512 + wn + ni * 16 + ec;
#pragma unroll
        for (int r = 0; r < 4; ++r) {
          const int mm = m0 + wm + mi * 16 + er + r;
          Vrow[(size_t)mm * 512 + n] = (__bf16)acc[mi][ni][r];
        }
      }
  }
}

// ---------------------------------------------------------------------------
// bf16 MFMA GEMM, double-buffered. MODE 1: +bias+resid; MODE 2: leaky-FFN.
// ---------------------------------------------------------------------------
template <int MODE>
__global__ __launch_bounds__(256) void gemm_bf16(
    const __bf16* __restrict__ A, const __bf16* __restrict__ W,
    const float* __restrict__ bias, const float* __restrict__ resid,
    float* __restrict__ C, int N) {
  __shared__ __bf16 As[2][128 * 32];
  __shared__ __bf16 Bs[2][128 * 32];
  const int tid = threadIdx.x;
  const int n0 = blockIdx.x * 128;
  const int m0 = blockIdx.y * 128;
  const int lane = tid & 63;
  const int w = tid >> 6;
  const int wm = (w & 1) * 64, wn = (w >> 1) * 64;
  const int fr = lane & 15, quad = lane >> 4;
  const int srow = lane >> 2;
  const int schunk = (lane & 3) ^ ((lane >> 3) & 3);

  f32x4 acc[4][4];
#pragma unroll
  for (int mi = 0; mi < 4; ++mi)
#pragma unroll
    for (int ni = 0; ni < 4; ++ni) acc[mi][ni] = (f32x4){0.f, 0.f, 0.f, 0.f};

#pragma unroll
  for (int j = 0; j < 2; ++j) {
    const int seg = w * 2 + j;
    const int row = seg * 16 + srow;
    gll16(&A[(size_t)(m0 + row) * 512 + schunk * 8], &As[0][seg * 512]);
    gll16(&W[(size_t)(n0 + row) * 512 + schunk * 8], &Bs[0][seg * 512]);
  }
  for (int it = 0; it < 16; ++it) {
    __syncthreads();
    if (it < 15) {
      const int kt = (it + 1) * 32, ib = (it + 1) & 1;
#pragma unroll
      for (int j = 0; j < 2; ++j) {
        const int seg = w * 2 + j;
        const int row = seg * 16 + srow;
        gll16(&A[(size_t)(m0 + row) * 512 + kt + schunk * 8], &As[ib][seg * 512]);
        gll16(&W[(size_t)(n0 + row) * 512 + kt + schunk * 8], &Bs[ib][seg * 512]);
      }
    }
    const __bf16* as = As[it & 1];
    const __bf16* bs = Bs[it & 1];
    bf16x8 af[4], bfv[4];
    const int rsw = (quad ^ ((fr >> 1) & 3)) * 8;
#pragma unroll
    for (int mi = 0; mi < 4; ++mi)
      af[mi] = *(const bf16x8*)&as[(wm + mi * 16 + fr) * 32 + rsw];
#pragma unroll
    for (int ni = 0; ni < 4; ++ni)
      bfv[ni] = *(const bf16x8*)&bs[(wn + ni * 16 + fr) * 32 + rsw];
#pragma unroll
    for (int mi = 0; mi < 4; ++mi)
#pragma unroll
      for (int ni = 0; ni < 4; ++ni)
        acc[mi][ni] = __builtin_amdgcn_mfma_f32_16x16x32_bf16(
            af[mi], bfv[ni], acc[mi][ni], 0, 0, 0);
  }

  const int er = quad * 4;
  const int ec = fr;
#pragma unroll
  for (int mi = 0; mi < 4; ++mi) {
#pragma unroll
    for (int ni = 0; ni < 4; ++ni) {
      const int n = n0 + wn + ni * 16 + ec;
      float bsv = bias[n];
#pragma unroll
      for (int r = 0; r < 4; ++r) {
        const int m = m0 + wm + mi * 16 + er + r;
        float v = acc[mi][ni][r];
        if (MODE == 1) {
          v += bsv + resid[(size_t)m * 512 + n];
        } else {
          float g = v + bsv;
          g = g > 0.f ? g : 0.01f * g;
          v = resid[(size_t)m * 512 + n] + g;
        }
        C[(size_t)m * N + n] = v;
      }
    }
  }
}

// ---------------------------------------------------------------------------
// V transpose: Vrow bf16 [b*1024+t][h*64+vd] -> Vt [bh][64 vd][1024 t].
// ---------------------------------------------------------------------------
__global__ __launch_bounds__(256) void v_transpose(
    const __bf16* __restrict__ Vrow, __bf16* __restrict__ Vt) {
  __shared__ __bf16 vt[64][136];
  const int bh = blockIdx.x;
  const int b = bh >> 3, h = bh & 7;
  const int sb = blockIdx.y * 128;
  const int tid = threadIdx.x;
#pragma unroll
  for (int i = 0; i < 8; ++i) {
    int idx = tid + i * 256;
    int t = idx >> 4, vd4 = (idx & 15) * 4;
    union { uint2 u; __bf16 e[4]; } v;
    v.u = *(const uint2*)&Vrow[((size_t)(b * 1024 + sb + t)) * 512 + h * 64 + vd4];
    vt[vd4 + 0][t] = v.e[0];
    vt[vd4 + 1][t] = v.e[1];
    vt[vd4 + 2][t] = v.e[2];
    vt[vd4 + 3][t] = v.e[3];
  }
  __syncthreads();
  {
    const int vd = tid >> 2, tseg = (tid & 3) * 32;
    uint4* o = (uint4*)(Vt + (size_t)bh * 65536 + (size_t)vd * 1024 + sb + tseg);
#pragma unroll
    for (int j = 0; j < 4; ++j)
      o[j] = *(const uint4*)&vt[vd][tseg + j * 8];
  }
}

// ---------------------------------------------------------------------------
// Split causal MFMA attention. Grid (64 bh, 24 entries); entry table gives
// (s-tile j, t-range). j<8: full range, write yb directly. j>=8: two halves
// write fp32 partials (acc 64x64 + zsum 64) to Pacc/Zb; attn_reduce combines.
// ---------------------------------------------------------------------------
__global__ __launch_bounds__(256) void attn_fused(
    const __bf16* __restrict__ Qg, const __bf16* __restrict__ Kg,
    const __bf16* __restrict__ Vt, const float* __restrict__ dist,
    const float* __restrict__ omega, __bf16* __restrict__ y,
    float* __restrict__ Pacc, float* __restrict__ Zb) {
  __shared__ __bf16 Ks[64 * 32];
  __shared__ __bf16 Vs[64 * 64];
  __shared__ __bf16 zbuf[4][16][72];

  const int bh = blockIdx.x;
  const int entry = blockIdx.y;
  const int b = bh >> 3, h = bh & 7;
  const int jidx = dJ[entry];
  const int tbeg = dTB[entry];
  const int tend = dTE[entry];
  const int s0 = jidx * 64;
  const int tid = threadIdx.x;
  const int lane = tid & 63;
  const int w = tid >> 6;
  const int q = lane >> 4;
  const int m = lane & 15;
  const float om = omega[h];

  const int sl = s0 + w * 16 + m;
  const bf16x8 bq = *(const bf16x8*)&Qg[((size_t)bh * 1024 + sl) * 32 + q * 8];
  const int kswz = (q ^ ((m >> 1) & 3)) * 8;

  f32x4 acc[4];
#pragma unroll
  for (int ni = 0; ni < 4; ++ni) acc[ni] = (f32x4){0.f, 0.f, 0.f, 0.f};
  float zsum = 0.0f;

  for (int tt = tbeg; tt < tend; ++tt) {
    const int t0 = tt * 64;
    __syncthreads();
    {
      int row = tid >> 2, p = tid & 3;
      uint4 v = *(const uint4*)&Kg[((size_t)bh * 1024 + t0 + row) * 32 + p * 8];
      *(uint4*)&Ks[row * 32 + ((p ^ ((row >> 1) & 3)) * 8)] = v;
    }
#pragma unroll
    for (int i = 0; i < 2; ++i) {
      int idx = tid + i * 256;
      int vd = idx >> 3, p = idx & 7;
      uint4 v = *(const uint4*)&Vt[(size_t)bh * 65536 + (size_t)vd * 1024 + t0 + p * 8];
      *(uint4*)&Vs[vd * 64 + ((p ^ (vd & 7)) * 8)] = v;
    }
    float4 dv[4];
#pragma unroll
    for (int mi = 0; mi < 4; ++mi)
      dv[mi] = *(const float4*)&dist[((size_t)b * 1024 + sl) * 1024 + t0 + 16 * mi + q * 4];
    __syncthreads();

#pragma unroll
    for (int mi = 0; mi < 4; ++mi) {
      const bf16x8 ak = *(const bf16x8*)&Ks[(16 * mi + m) * 32 + kswz];
      f32x4 s4 = __builtin_amdgcn_mfma_f32_16x16x32_bf16(
          ak, bq, (f32x4){0.f, 0.f, 0.f, 0.f}, 0, 0, 0);
      float zr[4];
#pragma unroll
      for (int r = 0; r < 4; ++r) {
        const int t = t0 + 16 * mi + q * 4 + r;
        float zv = __expf(s4[r] + __expf(-om * (&dv[mi].x)[r]) - 1.0f);
        zr[r] = (t <= sl) ? zv : 0.0f;
        zsum += zr[r];
      }
      union { __hip_bfloat162 h2[2]; uint2 u; } pz;
      pz.h2[0] = __float22bfloat162_rn(make_float2(zr[0], zr[1]));
      pz.h2[1] = __float22bfloat162_rn(make_float2(zr[2], zr[3]));
      *(uint2*)&zbuf[w][m][16 * mi + q * 4] = pz.u;
    }
    const bf16x8 az0 = *(const bf16x8*)&zbuf[w][m][q * 8];
    const bf16x8 az1 = *(const bf16x8*)&zbuf[w][m][32 + q * 8];
#pragma unroll
    for (int ni = 0; ni < 4; ++ni) {
      const bf16x8 vb0 = *(const bf16x8*)&Vs[(16 * ni + m) * 64 + ((q ^ (m & 7)) * 8)];
      const bf16x8 vb1 = *(const bf16x8*)&Vs[(16 * ni + m) * 64 + (((q + 4) ^ (m & 7)) * 8)];
      acc[ni] = __builtin_amdgcn_mfma_f32_16x16x32_bf16(az0, vb0, acc[ni], 0, 0, 0);
      acc[ni] = __builtin_amdgcn_mfma_f32_16x16x32_bf16(az1, vb1, acc[ni], 0, 0, 0);
    }
  }

  zsum += __shfl_xor(zsum, 16, 64);
  zsum += __shfl_xor(zsum, 32, 64);

  if (jidx < 8) {
#pragma unroll
    for (int r = 0; r < 4; ++r) {
      const float dn = __shfl(zsum, q * 4 + r, 64);
      const float inv = 1.0f / (dn + 1.0f);
      __bf16* yp = &y[((size_t)b * 1024 + s0 + w * 16 + q * 4 + r) * 512 + h * 64 + m];
#pragma unroll
      for (int ni = 0; ni < 4; ++ni)
        yp[ni * 16] = (__bf16)(acc[ni][r] * inv);
    }
  } else {
    const int half = (tbeg != 0) ? 1 : 0;
    const size_t pidx = (size_t)((bh * 8 + (jidx - 8)) * 2 + half);
    float* Pp = Pacc + pidx * 4096;
    float* Zp = Zb + pidx * 64;
#pragma unroll
    for (int r = 0; r < 4; ++r) {
      const int row = w * 16 + q * 4 + r;
      const float dn = __shfl(zsum, q * 4 + r, 64);
      if (m == 0) Zp[row] = dn;
#pragma unroll
      for (int ni = 0; ni < 4; ++ni)
        Pp[row * 64 + ni * 16 + m] = acc[ni][r];
    }
  }
}

// ---------------------------------------------------------------------------
// Combine the two halves of split s-tiles: y = (a0+a1)/(z0+z1+1), bf16 out.
// 512 blocks (bh x 8 split-tiles) x 256 thr; thread = (row, 16-col group).
// ---------------------------------------------------------------------------
__global__ __launch_bounds__(256) void attn_reduce(
    const float* __restrict__ Pacc, const float* __restrict__ Zb,
    __bf16* __restrict__ y) {
  const int e = blockIdx.x;
  const int bh = e >> 3, j = (e & 7) + 8;
  const int b = bh >> 3, h = bh & 7;
  const float* p0 = Pacc + (size_t)e * 2 * 4096;
  const float* p1 = p0 + 4096;
  const int row = threadIdx.x >> 2;
  const int c0 = (threadIdx.x & 3) * 16;
  const float z = Zb[(size_t)e * 128 + row] + Zb[(size_t)e * 128 + 64 + row];
  const float inv = 1.0f / (z + 1.0f);
  float4 o[4];
#pragma unroll
  for (int i = 0; i < 4; ++i) {
    const float4 a = *(const float4*)&p0[row * 64 + c0 + i * 4];
    const float4 c = *(const float4*)&p1[row * 64 + c0 + i * 4];
    o[i].x = (a.x + c.x) * inv; o[i].y = (a.y + c.y) * inv;
    o[i].z = (a.z + c.z) * inv; o[i].w = (a.w + c.w) * inv;
  }
  __bf16* yp = &y[((size_t)b * 1024 + j * 64 + row) * 512 + h * 64 + c0];
  *(uint4*)yp = pack8(o[0], o[1]);
  *(uint4*)(yp + 8) = pack8(o[2], o[3]);
}

// ---------------------------------------------------------------------------
// Row-wise LayerNorm: one wave per row, shfl-only (validated R6).
// ---------------------------------------------------------------------------
__global__ __launch_bounds__(256) void ln_kernel(
    const float* __restrict__ in, const float* __restrict__ w,
    const float* __restrict__ bvec, float* __restrict__ out,
    __bf16* __restrict__ outb) {
  const int row = blockIdx.x * 4 + (threadIdx.x >> 6);
  const int lane = threadIdx.x & 63;
  const float4* ip = (const float4*)(in + (size_t)row * 512);
  float4 a = ip[lane * 2], c = ip[lane * 2 + 1];
  float s = a.x + a.y + a.z + a.w + c.x + c.y + c.z + c.w;
#pragma unroll
  for (int off = 32; off > 0; off >>= 1) s += __shfl_xor(s, off, 64);
  const float mu = s * (1.0f / 512.0f);
  a.x -= mu; a.y -= mu; a.z -= mu; a.w -= mu;
  c.x -= mu; c.y -= mu; c.z -= mu; c.w -= mu;
  float s2 = a.x * a.x + a.y * a.y + a.z * a.z + a.w * a.w +
             c.x * c.x + c.y * c.y + c.z * c.z + c.w * c.w;
#pragma unroll
  for (int off = 32; off > 0; off >>= 1) s2 += __shfl_xor(s2, off, 64);
  const float inv = rsqrtf(s2 * (1.0f / 512.0f) + 1e-5f);
  const float4 w0 = ((const float4*)w)[lane * 2], w1 = ((const float4*)w)[lane * 2 + 1];
  const float4 b0 = ((const float4*)bvec)[lane * 2], b1 = ((const float4*)bvec)[lane * 2 + 1];
  float4 o0, o1;
  o0.x = a.x * inv * w0.x + b0.x; o0.y = a.y * inv * w0.y + b0.y;
  o0.z = a.z * inv * w0.z + b0.z; o0.w = a.w * inv * w0.w + b0.w;
  o1.x = c.x * inv * w1.x + b1.x; o1.y = c.y * inv * w1.y + b1.y;
  o1.z = c.z * inv * w1.z + b1.z; o1.w = c.w * inv * w1.w + b1.w;
  float4* op = (float4*)(out + (size_t)row * 512);
  op[lane * 2] = o0; op[lane * 2 + 1] = o1;
  if (outb) *(uint4*)&outb[(size_t)row * 512 + lane * 8] = pack8(o0, o1);
}

// ---------------------------------------------------------------------------
extern "C" void kernel_launch(void* const* d_in, const int* in_sizes, int n_in,
                              void* d_out, int out_size, void* d_ws, size_t ws_size,
                              hipStream_t stream) {
  const float* x = (const float*)d_in[0];
  // d_in[1] = attn_mask: deterministic causal triu(k=1) -> handled analytically
  const float* dist = (const float*)d_in[2];
  const float* Wq = (const float*)d_in[3];
  const float* Wk = (const float*)d_in[4];
  const float* Wv = (const float*)d_in[5];
  const float* omega = (const float*)d_in[6];
  const float* Wo = (const float*)d_in[7];
  const float* bo = (const float*)d_in[8];
  const float* Wf = (const float*)d_in[9];
  const float* bf_ = (const float*)d_in[10];
  const float* ln1w = (const float*)d_in[11];
  const float* ln1b = (const float*)d_in[12];
  const float* ln2w = (const float*)d_in[13];
  const float* ln2b = (const float*)d_in[14];
  float* out = (float*)d_out;

  // Workspace map (42.25 MB; phases never overlap in time):
  //  [0,8):   xb (dead after gemm_qkv) -> yb (attn/reduce out, gemm1 in)
  //  [8,9):   Wcat   [9,9.5): Wob   [9.5,10): Wfb
  //  [10,14): Qg     [14,18): Kg          (dead after attn)
  //  [18,26): Vrow (dead after v_transpose)
  //  [18,34): Pacc fp32 partials (attn) -> t1 fp32 (gemm1, after reduce)
  //  [34,42): Vt (dead after attn) -> t1b bf16 (ln1)
  //  [42,42.25): Zb
  char* base = (char*)d_ws;
  const size_t MB = 1 << 20;
  __bf16* xb = (__bf16*)base;
  __bf16* yb = (__bf16*)base;
  __bf16* Wcat = (__bf16*)(base + 8 * MB);
  __bf16* Wob = (__bf16*)(base + 9 * MB);
  __bf16* Wfb = (__bf16*)(base + 9 * MB + 512 * 1024);
  __bf16* Qg = (__bf16*)(base + 10 * MB);
  __bf16* Kg = (__bf16*)(base + 14 * MB);
  __bf16* Vrow = (__bf16*)(base + 18 * MB);
  float* Pacc = (float*)(base + 18 * MB);
  float* t1 = (float*)(base + 18 * MB);
  __bf16* Vt = (__bf16*)(base + 34 * MB);
  __bf16* t1b = (__bf16*)(base + 34 * MB);
  float* Zb = (float*)(base + 42 * MB);

  dim3 blk(256);
  // 0. all fp32 -> bf16 conversions
  cvt_all<<<dim3(2560), blk, 0, stream>>>(x, Wq, Wk, Wv, Wo, Wf,
                                          xb, Wcat, Wob, Wfb);
  // 1. QKV projection (dbuf) + fused l2norm -> Qg/Kg + Vrow
  gemm_qkv<<<dim3(8, 64), blk, 0, stream>>>(xb, Wcat, Qg, Kg, Vrow);
  // 2. Vrow -> Vt
  v_transpose<<<dim3(64, 8), blk, 0, stream>>>(Vrow, Vt);
  // 3. split causal attention -> yb (j<8) + partials (j>=8)
  attn_fused<<<dim3(64, 24), blk, 0, stream>>>(Qg, Kg, Vt, dist, omega, yb,
                                               Pacc, Zb);
  // 3b. combine split halves -> yb rows 512..1023 per (b,h)
  attn_reduce<<<dim3(512), blk, 0, stream>>>(Pacc, Zb, yb);
  // 4. out-proj + bias + residual -> t1 fp32 (dbuf)
  gemm_bf16<1><<<dim3(4, 64), blk, 0, stream>>>(yb, Wob, bo, x, t1, 512);
  // 5. LayerNorm1: t1 in-place + t1b bf16
  ln_kernel<<<dim3(2048), blk, 0, stream>>>(t1, ln1w, ln1b, t1, t1b);
  // 6. FFN + leaky-relu + residual -> d_out (dbuf)
  gemm_bf16<2><<<dim3(4, 64), blk, 0, stream>>>(t1b, Wfb, bf_, t1, out, 512);
  // 7. LayerNorm2 in-place on d_out
  ln_kernel<<<dim3(2048), blk, 0, stream>>>(out, ln2w, ln2b, out, nullptr);
}

// Round 9
// 227.712 us; speedup vs baseline: 1.1480x; 1.1480x over previous
//
#include <hip/hip_runtime.h>
#include <hip/hip_bf16.h>
#include <math.h>
#include <stdint.h>

// Problem constants
#define BB 8
#define SS 1024
#define DMM 512
#define HH 8
#define DKK 32
#define DHH 64
// M = BB*SS = 8192

typedef __bf16 bf16x8 __attribute__((ext_vector_type(8)));
typedef float f32x4 __attribute__((ext_vector_type(4)));

// async 16B global->LDS (gfx950). LDS dest = wave-uniform base + lane*16.
__device__ __forceinline__ void gll16(const void* g, void* l) {
  __builtin_amdgcn_global_load_lds(
      (const __attribute__((address_space(1))) void*)(uintptr_t)g,
      (__attribute__((address_space(3))) void*)(uint32_t)(uintptr_t)l,
      16, 0, 0);
}

__device__ __forceinline__ uint4 pack8(const float4 a, const float4 b) {
  union { __hip_bfloat162 h2[4]; uint4 u; } p;
  p.h2[0] = __float22bfloat162_rn(make_float2(a.x, a.y));
  p.h2[1] = __float22bfloat162_rn(make_float2(a.z, a.w));
  p.h2[2] = __float22bfloat162_rn(make_float2(b.x, b.y));
  p.h2[3] = __float22bfloat162_rn(make_float2(b.z, b.w));
  return p.u;
}

// Split-attention entry table: per bh, 24 blocks sorted by descending work.
// j = s-tile (64 rows); [tb,te) = t-tile range. j>=8 is split in two halves.
__device__ __constant__ unsigned char dJ[24]  = {15,15,14,7,14,13,13,12,6,12,11,11,10,5,10,9,9,8,4,8,3,2,1,0};
__device__ __constant__ unsigned char dTB[24] = {0,8,0,0,8,0,7,0,0,7,0,6,0,0,6,0,5,0,0,5,0,0,0,0};
__device__ __constant__ unsigned char dTE[24] = {8,16,8,8,15,7,14,7,7,13,6,12,6,6,11,5,10,5,5,9,4,3,2,1};

// ---------------------------------------------------------------------------
// One-shot fp32->bf16 conversion of x, Wq|Wk|Wv (->Wcat), Wo, Wf. 2560 blocks.
// ---------------------------------------------------------------------------
__global__ __launch_bounds__(256) void cvt_all(
    const float* __restrict__ x, const float* __restrict__ Wq,
    const float* __restrict__ Wk, const float* __restrict__ Wv,
    const float* __restrict__ Wo, const float* __restrict__ Wf,
    __bf16* __restrict__ xb, __bf16* __restrict__ Wcat,
    __bf16* __restrict__ Wob, __bf16* __restrict__ Wfb) {
  size_t i = ((size_t)blockIdx.x * 256 + threadIdx.x) * 8;
  const float* s;
  __bf16* d;
  size_t off;
  if (i < 4194304) { s = x; d = xb + i; off = i; }
  else {
    size_t j = i - 4194304;
    if (j < 524288) {
      d = Wcat + j;
      if (j < 131072) { s = Wq; off = j; }
      else if (j < 262144) { s = Wk; off = j - 131072; }
      else { s = Wv; off = j - 262144; }
    } else {
      size_t jj = j - 524288;
      if (jj < 262144) { s = Wo; d = Wob + jj; off = jj; }
      else { s = Wf; d = Wfb + (jj - 262144); off = jj - 262144; }
    }
  }
  float4 a = *(const float4*)&s[off];
  float4 b = *(const float4*)&s[off + 4];
  *(uint4*)d = pack8(a, b);
}

// ---------------------------------------------------------------------------
// 64x64-tile bf16 MFMA GEMM, BK=64, single-buffered, 4 waves (2x2), each wave
// 32x32 via 2x2 frags. Grid (m-tiles FAST, n-tiles): XCD = m%8 -> per-XCD
// working set = 1MB A-slice + full W (L2-resident).
// MODE 0: QKV + fused l2norm -> Qg/Kg bf16 planes + Vrow bf16.
// MODE 1: C = A@W^T + bias + resid (fp32).
// MODE 2: C = resid + leaky(A@W^T + bias) (fp32).
// LDS rows = 64 elems (8 chunks of 16B); source-chunk XOR swizzle gives
// 2-way bank aliasing on ds_read_b128 (free).
// ---------------------------------------------------------------------------
template <int MODE>
__global__ __launch_bounds__(256) void gemm64(
    const __bf16* __restrict__ A, const __bf16* __restrict__ W,
    const float* __restrict__ bias, const float* __restrict__ resid,
    float* __restrict__ C, __bf16* __restrict__ Qg, __bf16* __restrict__ Kg,
    __bf16* __restrict__ Vrow) {
  __shared__ __bf16 As[64 * 64];
  __shared__ __bf16 Bs[64 * 64];
  const int tid = threadIdx.x;
  const int m0 = blockIdx.x * 64;     // m fast -> XCD affinity
  const int n0 = blockIdx.y * 64;
  const int lane = tid & 63;
  const int w = tid >> 6;
  const int wm = (w & 1) * 32, wn = (w >> 1) * 32;
  const int fr = lane & 15, q = lane >> 4;
  const int r8 = lane >> 3;                 // 0..7 (row within 8-row group)
  const int c8 = (lane & 7) ^ (r8 & 7);     // swizzled global source chunk
  const int fswz = fr & 7;

  f32x4 acc[2][2];
#pragma unroll
  for (int mi = 0; mi < 2; ++mi)
#pragma unroll
    for (int ni = 0; ni < 2; ++ni) acc[mi][ni] = (f32x4){0.f, 0.f, 0.f, 0.f};

  for (int kt = 0; kt < 512; kt += 64) {
    __syncthreads();  // prior iter ds_reads done before overwrite
#pragma unroll
    for (int j = 0; j < 2; ++j) {
      const int row = w * 16 + j * 8;       // wave-uniform base row
      gll16(&A[(size_t)(m0 + row + r8) * 512 + kt + c8 * 8], &As[row * 64]);
      gll16(&W[(size_t)(n0 + row + r8) * 512 + kt + c8 * 8], &Bs[row * 64]);
    }
    __syncthreads();  // staged data visible

    bf16x8 af[2][2], bfv[2][2];
#pragma unroll
    for (int ks = 0; ks < 2; ++ks) {
#pragma unroll
      for (int mi = 0; mi < 2; ++mi)
        af[ks][mi] = *(const bf16x8*)&As[(wm + mi * 16 + fr) * 64 +
                                         (((ks * 4 + q) ^ fswz) * 8)];
#pragma unroll
      for (int ni = 0; ni < 2; ++ni)
        bfv[ks][ni] = *(const bf16x8*)&Bs[(wn + ni * 16 + fr) * 64 +
                                          (((ks * 4 + q) ^ fswz) * 8)];
    }
#pragma unroll
    for (int ks = 0; ks < 2; ++ks)
#pragma unroll
      for (int mi = 0; mi < 2; ++mi)
#pragma unroll
        for (int ni = 0; ni < 2; ++ni)
          acc[mi][ni] = __builtin_amdgcn_mfma_f32_16x16x32_bf16(
              af[ks][mi], bfv[ks][ni], acc[mi][ni], 0, 0, 0);
  }

  // epilogue: C/D col = fr, row = q*4 + r
  if (MODE == 0) {
    if (n0 < 512) {
      const bool isq = (n0 < 256);
      __bf16* G = isq ? Qg : Kg;
      const int hh = ((isq ? n0 : n0 - 256) + wn) >> 5;  // head index
#pragma unroll
      for (int mi = 0; mi < 2; ++mi) {
#pragma unroll
        for (int r = 0; r < 4; ++r) {
          float v0 = acc[mi][0][r], v1 = acc[mi][1][r];  // cols fr, 16+fr
          float ss = v0 * v0 + v1 * v1;
          ss += __shfl_xor(ss, 1, 64);
          ss += __shfl_xor(ss, 2, 64);
          ss += __shfl_xor(ss, 4, 64);
          ss += __shfl_xor(ss, 8, 64);
          const float sc = 1.0f / fmaxf(sqrtf(ss), 1e-12f);
          const int mm = m0 + wm + mi * 16 + q * 4 + r;
          const int bb = mm >> 10, s = mm & 1023;
          __bf16* gp = G + ((size_t)(bb * 8 + hh) * 1024 + s) * 32;
          gp[fr] = (__bf16)(v0 * sc);
          gp[16 + fr] = (__bf16)(v1 * sc);
        }
      }
    } else {
#pragma unroll
      for (int mi = 0; mi < 2; ++mi)
#pragma unroll
        for (int ni = 0; ni < 2; ++ni) {
          const int n = n0 - 512 + wn + ni * 16 + fr;
#pragma unroll
          for (int r = 0; r < 4; ++r) {
            const int mm = m0 + wm + mi * 16 + q * 4 + r;
            Vrow[(size_t)mm * 512 + n] = (__bf16)acc[mi][ni][r];
          }
        }
    }
  } else {
#pragma unroll
    for (int mi = 0; mi < 2; ++mi) {
#pragma unroll
      for (int ni = 0; ni < 2; ++ni) {
        const int n = n0 + wn + ni * 16 + fr;
        const float bsv = bias[n];
#pragma unroll
        for (int r = 0; r < 4; ++r) {
          const int m = m0 + wm + mi * 16 + q * 4 + r;
          float v = acc[mi][ni][r];
          if (MODE == 1) {
            v += bsv + resid[(size_t)m * 512 + n];
          } else {
            float g = v + bsv;
            g = g > 0.f ? g : 0.01f * g;
            v = resid[(size_t)m * 512 + n] + g;
          }
          C[(size_t)m * 512 + n] = v;
        }
      }
    }
  }
}

// ---------------------------------------------------------------------------
// V transpose: Vrow bf16 [b*1024+t][h*64+vd] -> Vt [bh][64 vd][1024 t].
// ---------------------------------------------------------------------------
__global__ __launch_bounds__(256) void v_transpose(
    const __bf16* __restrict__ Vrow, __bf16* __restrict__ Vt) {
  __shared__ __bf16 vt[64][136];
  const int bh = blockIdx.x;
  const int b = bh >> 3, h = bh & 7;
  const int sb = blockIdx.y * 128;
  const int tid = threadIdx.x;
#pragma unroll
  for (int i = 0; i < 8; ++i) {
    int idx = tid + i * 256;
    int t = idx >> 4, vd4 = (idx & 15) * 4;
    union { uint2 u; __bf16 e[4]; } v;
    v.u = *(const uint2*)&Vrow[((size_t)(b * 1024 + sb + t)) * 512 + h * 64 + vd4];
    vt[vd4 + 0][t] = v.e[0];
    vt[vd4 + 1][t] = v.e[1];
    vt[vd4 + 2][t] = v.e[2];
    vt[vd4 + 3][t] = v.e[3];
  }
  __syncthreads();
  {
    const int vd = tid >> 2, tseg = (tid & 3) * 32;
    uint4* o = (uint4*)(Vt + (size_t)bh * 65536 + (size_t)vd * 1024 + sb + tseg);
#pragma unroll
    for (int j = 0; j < 4; ++j)
      o[j] = *(const uint4*)&vt[vd][tseg + j * 8];
  }
}

// ---------------------------------------------------------------------------
// Split causal MFMA attention (validated R8). Grid (64 bh, 24 entries).
// ---------------------------------------------------------------------------
__global__ __launch_bounds__(256) void attn_fused(
    const __bf16* __restrict__ Qg, const __bf16* __restrict__ Kg,
    const __bf16* __restrict__ Vt, const float* __restrict__ dist,
    const float* __restrict__ omega, __bf16* __restrict__ y,
    float* __restrict__ Pacc, float* __restrict__ Zb) {
  __shared__ __bf16 Ks[64 * 32];
  __shared__ __bf16 Vs[64 * 64];
  __shared__ __bf16 zbuf[4][16][72];

  const int bh = blockIdx.x;
  const int entry = blockIdx.y;
  const int b = bh >> 3, h = bh & 7;
  const int jidx = dJ[entry];
  const int tbeg = dTB[entry];
  const int tend = dTE[entry];
  const int s0 = jidx * 64;
  const int tid = threadIdx.x;
  const int lane = tid & 63;
  const int w = tid >> 6;
  const int q = lane >> 4;
  const int m = lane & 15;
  const float om = omega[h];

  const int sl = s0 + w * 16 + m;
  const bf16x8 bq = *(const bf16x8*)&Qg[((size_t)bh * 1024 + sl) * 32 + q * 8];
  const int kswz = (q ^ ((m >> 1) & 3)) * 8;

  f32x4 acc[4];
#pragma unroll
  for (int ni = 0; ni < 4; ++ni) acc[ni] = (f32x4){0.f, 0.f, 0.f, 0.f};
  float zsum = 0.0f;

  for (int tt = tbeg; tt < tend; ++tt) {
    const int t0 = tt * 64;
    __syncthreads();
    {
      int row = tid >> 2, p = tid & 3;
      uint4 v = *(const uint4*)&Kg[((size_t)bh * 1024 + t0 + row) * 32 + p * 8];
      *(uint4*)&Ks[row * 32 + ((p ^ ((row >> 1) & 3)) * 8)] = v;
    }
#pragma unroll
    for (int i = 0; i < 2; ++i) {
      int idx = tid + i * 256;
      int vd = idx >> 3, p = idx & 7;
      uint4 v = *(const uint4*)&Vt[(size_t)bh * 65536 + (size_t)vd * 1024 + t0 + p * 8];
      *(uint4*)&Vs[vd * 64 + ((p ^ (vd & 7)) * 8)] = v;
    }
    float4 dv[4];
#pragma unroll
    for (int mi = 0; mi < 4; ++mi)
      dv[mi] = *(const float4*)&dist[((size_t)b * 1024 + sl) * 1024 + t0 + 16 * mi + q * 4];
    __syncthreads();

#pragma unroll
    for (int mi = 0; mi < 4; ++mi) {
      const bf16x8 ak = *(const bf16x8*)&Ks[(16 * mi + m) * 32 + kswz];
      f32x4 s4 = __builtin_amdgcn_mfma_f32_16x16x32_bf16(
          ak, bq, (f32x4){0.f, 0.f, 0.f, 0.f}, 0, 0, 0);
      float zr[4];
#pragma unroll
      for (int r = 0; r < 4; ++r) {
        const int t = t0 + 16 * mi + q * 4 + r;
        float zv = __expf(s4[r] + __expf(-om * (&dv[mi].x)[r]) - 1.0f);
        zr[r] = (t <= sl) ? zv : 0.0f;
        zsum += zr[r];
      }
      union { __hip_bfloat162 h2[2]; uint2 u; } pz;
      pz.h2[0] = __float22bfloat162_rn(make_float2(zr[0], zr[1]));
      pz.h2[1] = __float22bfloat162_rn(make_float2(zr[2], zr[3]));
      *(uint2*)&zbuf[w][m][16 * mi + q * 4] = pz.u;
    }
    const bf16x8 az0 = *(const bf16x8*)&zbuf[w][m][q * 8];
    const bf16x8 az1 = *(const bf16x8*)&zbuf[w][m][32 + q * 8];
#pragma unroll
    for (int ni = 0; ni < 4; ++ni) {
      const bf16x8 vb0 = *(const bf16x8*)&Vs[(16 * ni + m) * 64 + ((q ^ (m & 7)) * 8)];
      const bf16x8 vb1 = *(const bf16x8*)&Vs[(16 * ni + m) * 64 + (((q + 4) ^ (m & 7)) * 8)];
      acc[ni] = __builtin_amdgcn_mfma_f32_16x16x32_bf16(az0, vb0, acc[ni], 0, 0, 0);
      acc[ni] = __builtin_amdgcn_mfma_f32_16x16x32_bf16(az1, vb1, acc[ni], 0, 0, 0);
    }
  }

  zsum += __shfl_xor(zsum, 16, 64);
  zsum += __shfl_xor(zsum, 32, 64);

  if (jidx < 8) {
#pragma unroll
    for (int r = 0; r < 4; ++r) {
      const float dn = __shfl(zsum, q * 4 + r, 64);
      const float inv = 1.0f / (dn + 1.0f);
      __bf16* yp = &y[((size_t)b * 1024 + s0 + w * 16 + q * 4 + r) * 512 + h * 64 + m];
#pragma unroll
      for (int ni = 0; ni < 4; ++ni)
        yp[ni * 16] = (__bf16)(acc[ni][r] * inv);
    }
  } else {
    const int half = (tbeg != 0) ? 1 : 0;
    const size_t pidx = (size_t)((bh * 8 + (jidx - 8)) * 2 + half);
    float* Pp = Pacc + pidx * 4096;
    float* Zp = Zb + pidx * 64;
#pragma unroll
    for (int r = 0; r < 4; ++r) {
      const int row = w * 16 + q * 4 + r;
      const float dn = __shfl(zsum, q * 4 + r, 64);
      if (m == 0) Zp[row] = dn;
#pragma unroll
      for (int ni = 0; ni < 4; ++ni)
        Pp[row * 64 + ni * 16 + m] = acc[ni][r];
    }
  }
}

// ---------------------------------------------------------------------------
// Combine the two halves of split s-tiles: y = (a0+a1)/(z0+z1+1), bf16 out.
// ---------------------------------------------------------------------------
__global__ __launch_bounds__(256) void attn_reduce(
    const float* __restrict__ Pacc, const float* __restrict__ Zb,
    __bf16* __restrict__ y) {
  const int e = blockIdx.x;
  const int bh = e >> 3, j = (e & 7) + 8;
  const int b = bh >> 3, h = bh & 7;
  const float* p0 = Pacc + (size_t)e * 2 * 4096;
  const float* p1 = p0 + 4096;
  const int row = threadIdx.x >> 2;
  const int c0 = (threadIdx.x & 3) * 16;
  const float z = Zb[(size_t)e * 128 + row] + Zb[(size_t)e * 128 + 64 + row];
  const float inv = 1.0f / (z + 1.0f);
  float4 o[4];
#pragma unroll
  for (int i = 0; i < 4; ++i) {
    const float4 a = *(const float4*)&p0[row * 64 + c0 + i * 4];
    const float4 c = *(const float4*)&p1[row * 64 + c0 + i * 4];
    o[i].x = (a.x + c.x) * inv; o[i].y = (a.y + c.y) * inv;
    o[i].z = (a.z + c.z) * inv; o[i].w = (a.w + c.w) * inv;
  }
  __bf16* yp = &y[((size_t)b * 1024 + j * 64 + row) * 512 + h * 64 + c0];
  *(uint4*)yp = pack8(o[0], o[1]);
  *(uint4*)(yp + 8) = pack8(o[2], o[3]);
}

// ---------------------------------------------------------------------------
// Row-wise LayerNorm: one wave per row, shfl-only (validated R6).
// ---------------------------------------------------------------------------
__global__ __launch_bounds__(256) void ln_kernel(
    const float* __restrict__ in, const float* __restrict__ w,
    const float* __restrict__ bvec, float* __restrict__ out,
    __bf16* __restrict__ outb) {
  const int row = blockIdx.x * 4 + (threadIdx.x >> 6);
  const int lane = threadIdx.x & 63;
  const float4* ip = (const float4*)(in + (size_t)row * 512);
  float4 a = ip[lane * 2], c = ip[lane * 2 + 1];
  float s = a.x + a.y + a.z + a.w + c.x + c.y + c.z + c.w;
#pragma unroll
  for (int off = 32; off > 0; off >>= 1) s += __shfl_xor(s, off, 64);
  const float mu = s * (1.0f / 512.0f);
  a.x -= mu; a.y -= mu; a.z -= mu; a.w -= mu;
  c.x -= mu; c.y -= mu; c.z -= mu; c.w -= mu;
  float s2 = a.x * a.x + a.y * a.y + a.z * a.z + a.w * a.w +
             c.x * c.x + c.y * c.y + c.z * c.z + c.w * c.w;
#pragma unroll
  for (int off = 32; off > 0; off >>= 1) s2 += __shfl_xor(s2, off, 64);
  const float inv = rsqrtf(s2 * (1.0f / 512.0f) + 1e-5f);
  const float4 w0 = ((const float4*)w)[lane * 2], w1 = ((const float4*)w)[lane * 2 + 1];
  const float4 b0 = ((const float4*)bvec)[lane * 2], b1 = ((const float4*)bvec)[lane * 2 + 1];
  float4 o0, o1;
  o0.x = a.x * inv * w0.x + b0.x; o0.y = a.y * inv * w0.y + b0.y;
  o0.z = a.z * inv * w0.z + b0.z; o0.w = a.w * inv * w0.w + b0.w;
  o1.x = c.x * inv * w1.x + b1.x; o1.y = c.y * inv * w1.y + b1.y;
  o1.z = c.z * inv * w1.z + b1.z; o1.w = c.w * inv * w1.w + b1.w;
  float4* op = (float4*)(out + (size_t)row * 512);
  op[lane * 2] = o0; op[lane * 2 + 1] = o1;
  if (outb) *(uint4*)&outb[(size_t)row * 512 + lane * 8] = pack8(o0, o1);
}

// ---------------------------------------------------------------------------
extern "C" void kernel_launch(void* const* d_in, const int* in_sizes, int n_in,
                              void* d_out, int out_size, void* d_ws, size_t ws_size,
                              hipStream_t stream) {
  const float* x = (const float*)d_in[0];
  // d_in[1] = attn_mask: deterministic causal triu(k=1) -> handled analytically
  const float* dist = (const float*)d_in[2];
  const float* Wq = (const float*)d_in[3];
  const float* Wk = (const float*)d_in[4];
  const float* Wv = (const float*)d_in[5];
  const float* omega = (const float*)d_in[6];
  const float* Wo = (const float*)d_in[7];
  const float* bo = (const float*)d_in[8];
  const float* Wf = (const float*)d_in[9];
  const float* bf_ = (const float*)d_in[10];
  const float* ln1w = (const float*)d_in[11];
  const float* ln1b = (const float*)d_in[12];
  const float* ln2w = (const float*)d_in[13];
  const float* ln2b = (const float*)d_in[14];
  float* out = (float*)d_out;

  // Workspace map (42.25 MB; phases never overlap in time):
  //  [0,8):   xb (dead after gemm_qkv) -> yb (attn/reduce out, gemm1 in)
  //  [8,9):   Wcat   [9,9.5): Wob   [9.5,10): Wfb
  //  [10,14): Qg     [14,18): Kg          (dead after attn)
  //  [18,26): Vrow (dead after v_transpose)
  //  [18,34): Pacc fp32 partials (attn) -> t1 fp32 (gemm1, after reduce)
  //  [34,42): Vt (dead after attn) -> t1b bf16 (ln1)
  //  [42,42.25): Zb
  char* base = (char*)d_ws;
  const size_t MB = 1 << 20;
  __bf16* xb = (__bf16*)base;
  __bf16* yb = (__bf16*)base;
  __bf16* Wcat = (__bf16*)(base + 8 * MB);
  __bf16* Wob = (__bf16*)(base + 9 * MB);
  __bf16* Wfb = (__bf16*)(base + 9 * MB + 512 * 1024);
  __bf16* Qg = (__bf16*)(base + 10 * MB);
  __bf16* Kg = (__bf16*)(base + 14 * MB);
  __bf16* Vrow = (__bf16*)(base + 18 * MB);
  float* Pacc = (float*)(base + 18 * MB);
  float* t1 = (float*)(base + 18 * MB);
  __bf16* Vt = (__bf16*)(base + 34 * MB);
  __bf16* t1b = (__bf16*)(base + 34 * MB);
  float* Zb = (float*)(base + 42 * MB);

  dim3 blk(256);
  // 0. all fp32 -> bf16 conversions
  cvt_all<<<dim3(2560), blk, 0, stream>>>(x, Wq, Wk, Wv, Wo, Wf,
                                          xb, Wcat, Wob, Wfb);
  // 1. QKV projection (64-tile, 2048 blocks) + fused l2norm -> Qg/Kg + Vrow
  gemm64<0><<<dim3(128, 16), blk, 0, stream>>>(xb, Wcat, nullptr, nullptr,
                                               nullptr, Qg, Kg, Vrow);
  // 2. Vrow -> Vt
  v_transpose<<<dim3(64, 8), blk, 0, stream>>>(Vrow, Vt);
  // 3. split causal attention -> yb (j<8) + partials (j>=8)
  attn_fused<<<dim3(64, 24), blk, 0, stream>>>(Qg, Kg, Vt, dist, omega, yb,
                                               Pacc, Zb);
  // 3b. combine split halves -> yb rows 512..1023 per (b,h)
  attn_reduce<<<dim3(512), blk, 0, stream>>>(Pacc, Zb, yb);
  // 4. out-proj + bias + residual -> t1 fp32 (64-tile, 1024 blocks)
  gemm64<1><<<dim3(128, 8), blk, 0, stream>>>(yb, Wob, bo, x, t1,
                                              nullptr, nullptr, nullptr);
  // 5. LayerNorm1: t1 in-place + t1b bf16
  ln_kernel<<<dim3(2048), blk, 0, stream>>>(t1, ln1w, ln1b, t1, t1b);
  // 6. FFN + leaky-relu + residual -> d_out (64-tile, 1024 blocks)
  gemm64<2><<<dim3(128, 8), blk, 0, stream>>>(t1b, Wfb, bf_, t1, out,
                                              nullptr, nullptr, nullptr);
  // 7. LayerNorm2 in-place on d_out
  ln_kernel<<<dim3(2048), blk, 0, stream>>>(out, ln2w, ln2b, out, nullptr);
}